// Round 5
// baseline (74.771 us; speedup 1.0000x reference)
//
#include <hip/hip_runtime.h>
#include <cmath>

#define D 4096

typedef float fvec4 __attribute__((ext_vector_type(4)));

__device__ __forceinline__ float wave_reduce_sum(float v) {
#pragma unroll
    for (int off = 32; off > 0; off >>= 1)
        v += __shfl_down(v, off, 64);
    return v;
}

__device__ __forceinline__ float sigmoidf(float x) {
    return 1.0f / (1.0f + expf(-x));
}

// ws layout (floats):
//   [0 .. 4095]        q
//   [4096 .. 8191]     k (already scaled by 1/sqrt(D))
//   [8192 .. 12287]    v
//   [12288 .. 16383]   o = sigmoid(w_o@x + b_o)
//   [16384]            raw i dot (w_i@x + b_i)
//   [16385]            raw f dot (w_f@x + b_f)

// Kernel A: 4 fused matvecs (q,k,v,o) + i/f row dots.
// 1024 blocks x 16 rows (4 rows per wave) so the 16 KB x-staging is
// amortized 16x (x traffic 64 MB -> 16 MB; per-CU load path is the ceiling).
__global__ __launch_bounds__(256) void gates_kernel(
    const float* __restrict__ x,
    const float* __restrict__ wq, const float* __restrict__ bq,
    const float* __restrict__ wk, const float* __restrict__ bk,
    const float* __restrict__ wv, const float* __restrict__ bv,
    const float* __restrict__ wi, const float* __restrict__ bi,
    const float* __restrict__ wf, const float* __restrict__ bfv,
    const float* __restrict__ wo, const float* __restrict__ bo,
    float* __restrict__ ws)
{
    __shared__ float xs[D];
    const int tid = threadIdx.x;
    fvec4* xs4 = (fvec4*)xs;
    const fvec4* x4 = (const fvec4*)x;
#pragma unroll
    for (int i = 0; i < 4; ++i) xs4[tid + i * 256] = x4[tid + i * 256];
    __syncthreads();

    const int wave = tid >> 6;
    const int lane = tid & 63;

    if (blockIdx.x == 1024) {
        // i_t and f_t raw dots (rows of w_i, w_f)
        if (wave < 2) {
            const fvec4* W4 = (const fvec4*)(wave == 0 ? wi : wf);
            float acc = 0.f;
#pragma unroll
            for (int it = 0; it < 16; ++it) {
                fvec4 w = W4[it * 64 + lane];
                fvec4 xv = xs4[it * 64 + lane];
                acc += w.x * xv.x + w.y * xv.y + w.z * xv.z + w.w * xv.w;
            }
            acc = wave_reduce_sum(acc);
            if (lane == 0) {
                float b = (wave == 0) ? bi[0] : bfv[0];
                ws[16384 + wave] = acc + b;
            }
        }
        return;
    }

    // 4 consecutive rows per wave; groups are 4-aligned so they never
    // straddle a matrix boundary (boundaries at multiples of 4096).
    const int base = blockIdx.x * 16 + wave * 4;   // [0, 16384)
    const int m = base >> 12;                      // which matrix
    const int row0 = base & 4095;
    const float* W = (m == 0) ? wq : (m == 1) ? wk : (m == 2) ? wv : wo;

#pragma unroll
    for (int r = 0; r < 4; ++r) {
        const int row = row0 + r;
        const fvec4* W4 = (const fvec4*)(W + (size_t)row * D);
        float acc0 = 0.f, acc1 = 0.f;
#pragma unroll
        for (int it = 0; it < 16; it += 2) {
            fvec4 w0 = W4[it * 64 + lane];
            fvec4 w1 = W4[(it + 1) * 64 + lane];
            fvec4 xv0 = xs4[it * 64 + lane];
            fvec4 xv1 = xs4[(it + 1) * 64 + lane];
            acc0 += w0.x * xv0.x + w0.y * xv0.y + w0.z * xv0.z + w0.w * xv0.w;
            acc1 += w1.x * xv1.x + w1.y * xv1.y + w1.z * xv1.z + w1.w * xv1.w;
        }
        float acc = wave_reduce_sum(acc0 + acc1);
        if (lane == 0) {
            if (m == 0)      ws[row]         = acc + bq[row];
            else if (m == 1) ws[4096 + row]  = (acc + bk[row]) * 0.015625f; // 1/sqrt(4096)
            else if (m == 2) ws[8192 + row]  = acc + bv[row];
            else             ws[12288 + row] = sigmoidf(acc + bo[row]);
        }
    }
}

// Kernel B: fully fused cell + output.
//   c_t = f*c_prev + i*v(x)k   (streamed, nt)
//   per-row dot c_prev[row,:].q  ->  h[row] = o*(f*dot + i*kq*v)*inv
//   kq = k.q and npq = n_prev.q computed redundantly per block from the
//   already-LDS-staged k,q (identical fp32 result in every block).
//   n_t written by the first 8 threads of each block.
// 512 blocks x 8 rows (2 rows per wave): q/k staging 32 MB -> 16 MB.
__global__ __launch_bounds__(256) void cell_kernel(
    const float* __restrict__ c_prev,
    const float* __restrict__ n_prev,
    const float* __restrict__ ws,
    float* __restrict__ c_out,
    float* __restrict__ out)
{
    __shared__ float ks[D];
    __shared__ float qs[D];
    __shared__ float red[8];
    const int tid = threadIdx.x;
    const int wave = tid >> 6;
    const int lane = tid & 63;

    fvec4* ks4 = (fvec4*)ks;
    fvec4* qs4 = (fvec4*)qs;
    const fvec4* k4g = (const fvec4*)(ws + D);
    const fvec4* q4g = (const fvec4*)ws;
    const fvec4* np4 = (const fvec4*)n_prev;
#pragma unroll
    for (int i = 0; i < 4; ++i) {
        ks4[tid + i * 256] = k4g[tid + i * 256];
        qs4[tid + i * 256] = q4g[tid + i * 256];
    }
    __syncthreads();

    // block-wide kq = k.q and npq = n_prev.q
    float kq = 0.f, npq = 0.f;
#pragma unroll
    for (int i = 0; i < 4; ++i) {
        int j = tid + i * 256;
        fvec4 q = qs4[j], k = ks4[j], np = np4[j];
        kq  += k.x * q.x + k.y * q.y + k.z * q.z + k.w * q.w;
        npq += np.x * q.x + np.y * q.y + np.z * q.z + np.w * q.w;
    }
    kq = wave_reduce_sum(kq);
    npq = wave_reduce_sum(npq);
    if (lane == 0) { red[wave] = kq; red[4 + wave] = npq; }
    __syncthreads();
    kq  = (red[0] + red[1]) + (red[2] + red[3]);
    npq = (red[4] + red[5]) + (red[6] + red[7]);

    const float i_t = expf(ws[16384]);
    const float f_t = sigmoidf(ws[16385]);
    const float nqt = f_t * npq + i_t * kq;          // n_t . q
    const float inv = 1.0f / fmaxf(fabsf(nqt), 1.0f);

#pragma unroll
    for (int rr = 0; rr < 2; ++rr) {
        const int row = blockIdx.x * 8 + wave * 2 + rr;   // [0, 4096)
        const float v  = ws[8192 + row];
        const float vr = v * i_t;                          // i_t * v[row]
        const float o  = ws[12288 + row];
        const fvec4* cp4 = (const fvec4*)(c_prev + (size_t)row * D);
        fvec4* co4 = (fvec4*)(c_out + (size_t)row * D);
        float dot = 0.f;
#pragma unroll
        for (int it = 0; it < 16; ++it) {
            int j = it * 64 + lane;
            fvec4 cp = __builtin_nontemporal_load(&cp4[j]);
            fvec4 kk = ks4[j];
            fvec4 qq = qs4[j];
            fvec4 ct;
            ct.x = f_t * cp.x + vr * kk.x;
            ct.y = f_t * cp.y + vr * kk.y;
            ct.z = f_t * cp.z + vr * kk.z;
            ct.w = f_t * cp.w + vr * kk.w;
            __builtin_nontemporal_store(ct, &co4[j]);
            dot += cp.x * qq.x + cp.y * qq.y + cp.z * qq.z + cp.w * qq.w;
        }
        dot = wave_reduce_sum(dot);
        if (lane == 0) {
            // h[row] = o * h_tilde[row]
            out[row] = o * (f_t * dot + i_t * kq * v) * inv;
        }
    }

    // n_t for this block's 8 rows
    if (tid < 8) {
        const int idx = blockIdx.x * 8 + tid;
        out[(size_t)4096 + (size_t)D * D + idx] = f_t * n_prev[idx] + i_t * ks[idx];
    }
}

extern "C" void kernel_launch(void* const* d_in, const int* in_sizes, int n_in,
                              void* d_out, int out_size, void* d_ws, size_t ws_size,
                              hipStream_t stream)
{
    const float* x      = (const float*)d_in[0];
    const float* c_prev = (const float*)d_in[1];
    const float* n_prev = (const float*)d_in[2];
    const float* wq = (const float*)d_in[3];  const float* bq  = (const float*)d_in[4];
    const float* wk = (const float*)d_in[5];  const float* bk  = (const float*)d_in[6];
    const float* wv = (const float*)d_in[7];  const float* bv  = (const float*)d_in[8];
    const float* wi = (const float*)d_in[9];  const float* bi  = (const float*)d_in[10];
    const float* wf = (const float*)d_in[11]; const float* bfv = (const float*)d_in[12];
    const float* wo = (const float*)d_in[13]; const float* bo  = (const float*)d_in[14];
    float* out = (float*)d_out;
    float* ws  = (float*)d_ws;

    gates_kernel<<<dim3(1025), dim3(256), 0, stream>>>(
        x, wq, bq, wk, bk, wv, bv, wi, bi, wf, bfv, wo, bo, ws);
    cell_kernel<<<dim3(512), dim3(256), 0, stream>>>(c_prev, n_prev, ws, out + D, out);
}

// Round 6
// 73.817 us; speedup vs baseline: 1.0129x; 1.0129x over previous
//
#include <hip/hip_runtime.h>
#include <cmath>

#define D 4096

typedef float fvec4 __attribute__((ext_vector_type(4)));

__device__ __forceinline__ float wave_reduce_sum(float v) {
#pragma unroll
    for (int off = 32; off > 0; off >>= 1)
        v += __shfl_down(v, off, 64);
    return v;
}

__device__ __forceinline__ float sigmoidf(float x) {
    return 1.0f / (1.0f + expf(-x));
}

// ws layout (floats):
//   [0 .. 4095]        q
//   [4096 .. 8191]     k (already scaled by 1/sqrt(D))
//   [8192 .. 12287]    v
//   [12288 .. 16383]   o = sigmoid(w_o@x + b_o)
//   [16384]            raw i dot (w_i@x + b_i)
//   [16385]            raw f dot (w_f@x + b_f)
//   [16386]            kq = k . q
//   [16387]            npq = n_prev . q
//   [16388 .. 20483]   cprevq[row] = c_prev[row,:] . q

// Kernel 1: q,k,v matvecs (192 MB of weight reads) + i/f dots.
// One row per wave, R2-proven interleaved form.
__global__ __launch_bounds__(256) void qkv_kernel(
    const float* __restrict__ x,
    const float* __restrict__ wq, const float* __restrict__ bq,
    const float* __restrict__ wk, const float* __restrict__ bk,
    const float* __restrict__ wv, const float* __restrict__ bv,
    const float* __restrict__ wi, const float* __restrict__ bi,
    const float* __restrict__ wf, const float* __restrict__ bfv,
    float* __restrict__ ws)
{
    __shared__ float xs[D];
    const int tid = threadIdx.x;
    fvec4* xs4 = (fvec4*)xs;
    const fvec4* x4 = (const fvec4*)x;
#pragma unroll
    for (int i = 0; i < 4; ++i) xs4[tid + i * 256] = x4[tid + i * 256];
    __syncthreads();

    const int wave = tid >> 6;
    const int lane = tid & 63;

    if (blockIdx.x == 3072) {
        if (wave < 2) {
            const fvec4* W4 = (const fvec4*)(wave == 0 ? wi : wf);
            float acc = 0.f;
#pragma unroll
            for (int it = 0; it < 16; ++it) {
                fvec4 w = W4[it * 64 + lane];
                fvec4 xv = xs4[it * 64 + lane];
                acc += w.x * xv.x + w.y * xv.y + w.z * xv.z + w.w * xv.w;
            }
            acc = wave_reduce_sum(acc);
            if (lane == 0) {
                float b = (wave == 0) ? bi[0] : bfv[0];
                ws[16384 + wave] = acc + b;
            }
        }
        return;
    }

    const int rid = blockIdx.x * 4 + wave;     // [0, 12288)
    const int m = rid >> 12;                   // 0:q 1:k 2:v
    const int row = rid & 4095;
    const float* W = (m == 0) ? wq : (m == 1) ? wk : wv;
    const fvec4* W4 = (const fvec4*)(W + (size_t)row * D);
    float acc0 = 0.f, acc1 = 0.f;
#pragma unroll
    for (int it = 0; it < 16; it += 2) {
        fvec4 w0 = W4[it * 64 + lane];
        fvec4 w1 = W4[(it + 1) * 64 + lane];
        fvec4 xv0 = xs4[it * 64 + lane];
        fvec4 xv1 = xs4[(it + 1) * 64 + lane];
        acc0 += w0.x * xv0.x + w0.y * xv0.y + w0.z * xv0.z + w0.w * xv0.w;
        acc1 += w1.x * xv1.x + w1.y * xv1.y + w1.z * xv1.z + w1.w * xv1.w;
    }
    float acc = wave_reduce_sum(acc0 + acc1);
    if (lane == 0) {
        if (m == 0)      ws[row]        = acc + bq[row];
        else if (m == 1) ws[4096 + row] = (acc + bk[row]) * 0.015625f; // 1/sqrt(4096)
        else             ws[8192 + row] = acc + bv[row];
    }
}

// Kernel 2: cell stream (even blocks) CONCURRENT with w_o matvec (odd blocks).
// Even b: 4 cell rows (1/wave): c_t = f*c_prev + i*v(x)k (nt), dot c_prev.q.
// Odd  b: 4 w_o rows (1/wave): o = sigmoid(w_o@x + b_o).
// Block 2048: kq = k.q, npq = n_prev.q.
// Shared 32 KB buffer: cell uses [k | q]; w_o uses [x | unused].
__global__ __launch_bounds__(256) void cell_wo_kernel(
    const float* __restrict__ c_prev,
    const float* __restrict__ n_prev,
    const float* __restrict__ x,
    const float* __restrict__ wo, const float* __restrict__ bo,
    float* __restrict__ ws,
    float* __restrict__ c_out)
{
    __shared__ float sbuf[2 * D];
    const int tid = threadIdx.x;
    const int wave = tid >> 6;
    const int lane = tid & 63;
    fvec4* s4 = (fvec4*)sbuf;

    if (blockIdx.x == 2048) {
        __shared__ float red[8];
        const fvec4* q4 = (const fvec4*)ws;
        const fvec4* k4 = (const fvec4*)(ws + D);
        const fvec4* np4 = (const fvec4*)n_prev;
        float kq = 0.f, npq = 0.f;
#pragma unroll
        for (int i = 0; i < 4; ++i) {
            int j = tid + i * 256;
            fvec4 q = q4[j], k = k4[j], np = np4[j];
            kq  += k.x * q.x + k.y * q.y + k.z * q.z + k.w * q.w;
            npq += np.x * q.x + np.y * q.y + np.z * q.z + np.w * q.w;
        }
        kq = wave_reduce_sum(kq);
        npq = wave_reduce_sum(npq);
        if (lane == 0) { red[wave] = kq; red[4 + wave] = npq; }
        __syncthreads();
        if (tid == 0) {
            ws[16386] = (red[0] + red[1]) + (red[2] + red[3]);
            ws[16387] = (red[4] + red[5]) + (red[6] + red[7]);
        }
        return;
    }

    const int unit = blockIdx.x >> 1;          // [0, 1024)

    if (blockIdx.x & 1) {
        // ---- w_o matvec: 4 rows, one per wave ----
        const fvec4* x4 = (const fvec4*)x;
#pragma unroll
        for (int i = 0; i < 4; ++i) s4[tid + i * 256] = x4[tid + i * 256];
        __syncthreads();

        const int row = unit * 4 + wave;       // [0, 4096)
        const fvec4* W4 = (const fvec4*)(wo + (size_t)row * D);
        float acc0 = 0.f, acc1 = 0.f;
#pragma unroll
        for (int it = 0; it < 16; it += 2) {
            fvec4 w0 = W4[it * 64 + lane];
            fvec4 w1 = W4[(it + 1) * 64 + lane];
            fvec4 xv0 = s4[it * 64 + lane];
            fvec4 xv1 = s4[(it + 1) * 64 + lane];
            acc0 += w0.x * xv0.x + w0.y * xv0.y + w0.z * xv0.z + w0.w * xv0.w;
            acc1 += w1.x * xv1.x + w1.y * xv1.y + w1.z * xv1.z + w1.w * xv1.w;
        }
        float acc = wave_reduce_sum(acc0 + acc1);
        if (lane == 0) ws[12288 + row] = sigmoidf(acc + bo[row]);
    } else {
        // ---- cell stream: 4 rows, one per wave ----
        fvec4* ks4 = s4;                       // sbuf[0 .. 4095] = k
        fvec4* qs4 = s4 + D / 4;               // sbuf[4096 .. 8191] = q
        const fvec4* k4g = (const fvec4*)(ws + D);
        const fvec4* q4g = (const fvec4*)ws;
#pragma unroll
        for (int i = 0; i < 4; ++i) {
            ks4[tid + i * 256] = k4g[tid + i * 256];
            qs4[tid + i * 256] = q4g[tid + i * 256];
        }
        __syncthreads();

        const float i_t = expf(ws[16384]);
        const float f_t = sigmoidf(ws[16385]);

        const int row = unit * 4 + wave;       // [0, 4096)
        const float vr = ws[8192 + row] * i_t; // i_t * v[row]
        const fvec4* cp4 = (const fvec4*)(c_prev + (size_t)row * D);
        fvec4* co4 = (fvec4*)(c_out + (size_t)row * D);
        float dot = 0.f;
#pragma unroll
        for (int it = 0; it < 16; ++it) {
            int j = it * 64 + lane;
            fvec4 cp = __builtin_nontemporal_load(&cp4[j]);
            fvec4 kk = ks4[j];
            fvec4 qq = qs4[j];
            fvec4 ct;
            ct.x = f_t * cp.x + vr * kk.x;
            ct.y = f_t * cp.y + vr * kk.y;
            ct.z = f_t * cp.z + vr * kk.z;
            ct.w = f_t * cp.w + vr * kk.w;
            __builtin_nontemporal_store(ct, &co4[j]);
            dot += cp.x * qq.x + cp.y * qq.y + cp.z * qq.z + cp.w * qq.w;
        }
        dot = wave_reduce_sum(dot);
        if (lane == 0) ws[16388 + row] = dot;
    }
}

// Kernel 3: n_t, h_t (4096 threads)
__global__ __launch_bounds__(256) void finalize_kernel(
    const float* __restrict__ n_prev,
    const float* __restrict__ ws,
    float* __restrict__ out)
{
    const int idx = blockIdx.x * 256 + threadIdx.x;
    const float i_t = expf(ws[16384]);
    const float f_t = sigmoidf(ws[16385]);
    const float kq  = ws[16386];
    const float npq = ws[16387];
    const float nqt = f_t * npq + i_t * kq;          // n_t . q
    const float inv = 1.0f / fmaxf(fabsf(nqt), 1.0f);

    const float k = ws[4096 + idx];
    const float v = ws[8192 + idx];
    const float o = ws[12288 + idx];
    const float cpq = ws[16388 + idx];

    const float h_tilde = (f_t * cpq + i_t * kq * v) * inv;
    out[idx] = o * h_tilde;                            // h_t
    out[(size_t)4096 + (size_t)D * D + idx] = f_t * n_prev[idx] + i_t * k;  // n_t
}

extern "C" void kernel_launch(void* const* d_in, const int* in_sizes, int n_in,
                              void* d_out, int out_size, void* d_ws, size_t ws_size,
                              hipStream_t stream)
{
    const float* x      = (const float*)d_in[0];
    const float* c_prev = (const float*)d_in[1];
    const float* n_prev = (const float*)d_in[2];
    const float* wq = (const float*)d_in[3];  const float* bq  = (const float*)d_in[4];
    const float* wk = (const float*)d_in[5];  const float* bk  = (const float*)d_in[6];
    const float* wv = (const float*)d_in[7];  const float* bv  = (const float*)d_in[8];
    const float* wi = (const float*)d_in[9];  const float* bi  = (const float*)d_in[10];
    const float* wf = (const float*)d_in[11]; const float* bfv = (const float*)d_in[12];
    const float* wo = (const float*)d_in[13]; const float* bo  = (const float*)d_in[14];
    float* out = (float*)d_out;
    float* ws  = (float*)d_ws;

    qkv_kernel<<<dim3(3073), dim3(256), 0, stream>>>(
        x, wq, bq, wk, bk, wv, bv, wi, bi, wf, bfv, ws);
    cell_wo_kernel<<<dim3(2049), dim3(256), 0, stream>>>(
        c_prev, n_prev, x, wo, bo, ws, out + D);
    finalize_kernel<<<dim3(16), dim3(256), 0, stream>>>(n_prev, ws, out);
}

// Round 8
// 70.185 us; speedup vs baseline: 1.0653x; 1.0518x over previous
//
#include <hip/hip_runtime.h>
#include <cmath>

#define D 4096

typedef float fvec4 __attribute__((ext_vector_type(4)));

__device__ __forceinline__ float wave_reduce_sum(float v) {
#pragma unroll
    for (int off = 32; off > 0; off >>= 1)
        v += __shfl_down(v, off, 64);
    return v;
}

__device__ __forceinline__ float sigmoidf(float x) {
    return 1.0f / (1.0f + expf(-x));
}

// ws layout (floats):
//   [0 .. 4095]   q
//   [4096 .. 8191] k (already scaled by 1/sqrt(D))
//   [16384]       raw i dot (w_i@x + b_i)
//   [16385]       raw f dot (w_f@x + b_f)

// Kernel 1: q,k matvecs (128 MB weight reads) + i/f dots.
// One row of wq AND one row of wk per wave (interleaved load streams).
__global__ __launch_bounds__(256) void qk_kernel(
    const float* __restrict__ x,
    const float* __restrict__ wq, const float* __restrict__ bq,
    const float* __restrict__ wk, const float* __restrict__ bk,
    const float* __restrict__ wi, const float* __restrict__ bi,
    const float* __restrict__ wf, const float* __restrict__ bfv,
    float* __restrict__ ws)
{
    __shared__ float xs[D];
    const int tid = threadIdx.x;
    fvec4* xs4 = (fvec4*)xs;
    const fvec4* x4 = (const fvec4*)x;
#pragma unroll
    for (int i = 0; i < 4; ++i) xs4[tid + i * 256] = x4[tid + i * 256];
    __syncthreads();

    const int wave = tid >> 6;
    const int lane = tid & 63;

    if (blockIdx.x == 1024) {
        if (wave < 2) {
            const fvec4* W4 = (const fvec4*)(wave == 0 ? wi : wf);
            float acc = 0.f;
#pragma unroll
            for (int it = 0; it < 16; ++it) {
                fvec4 w = W4[it * 64 + lane];
                fvec4 xv = xs4[it * 64 + lane];
                acc += w.x * xv.x + w.y * xv.y + w.z * xv.z + w.w * xv.w;
            }
            acc = wave_reduce_sum(acc);
            if (lane == 0) {
                float b = (wave == 0) ? bi[0] : bfv[0];
                ws[16384 + wave] = acc + b;
            }
        }
        return;
    }

    const int row = blockIdx.x * 4 + wave;         // [0, 4096)
    const fvec4* Wq4 = (const fvec4*)(wq + (size_t)row * D);
    const fvec4* Wk4 = (const fvec4*)(wk + (size_t)row * D);
    float aq0 = 0.f, aq1 = 0.f, ak0 = 0.f, ak1 = 0.f;
#pragma unroll
    for (int it = 0; it < 16; it += 2) {
        fvec4 q0 = Wq4[it * 64 + lane];
        fvec4 q1 = Wq4[(it + 1) * 64 + lane];
        fvec4 k0 = Wk4[it * 64 + lane];
        fvec4 k1 = Wk4[(it + 1) * 64 + lane];
        fvec4 xv0 = xs4[it * 64 + lane];
        fvec4 xv1 = xs4[(it + 1) * 64 + lane];
        aq0 += q0.x * xv0.x + q0.y * xv0.y + q0.z * xv0.z + q0.w * xv0.w;
        aq1 += q1.x * xv1.x + q1.y * xv1.y + q1.z * xv1.z + q1.w * xv1.w;
        ak0 += k0.x * xv0.x + k0.y * xv0.y + k0.z * xv0.z + k0.w * xv0.w;
        ak1 += k1.x * xv1.x + k1.y * xv1.y + k1.z * xv1.z + k1.w * xv1.w;
    }
    float accq = wave_reduce_sum(aq0 + aq1);
    float acck = wave_reduce_sum(ak0 + ak1);
    if (lane == 0) {
        ws[row]        = accq + bq[row];
        ws[4096 + row] = (acck + bk[row]) * 0.015625f;   // 1/sqrt(4096)
    }
}

// Kernel 2: fused v/o matvecs + cell stream + h/n epilogue.
// Block b owns rows 4b..4b+3: computes v,o for those rows (row-local),
// block-redundant kq/npq, then streams c_prev -> c_t with fused dot.
__global__ __launch_bounds__(256) void vocell_kernel(
    const float* __restrict__ x,
    const float* __restrict__ c_prev,
    const float* __restrict__ n_prev,
    const float* __restrict__ wv, const float* __restrict__ bv,
    const float* __restrict__ wo, const float* __restrict__ bo,
    const float* __restrict__ ws,
    float* __restrict__ c_out,
    float* __restrict__ out)
{
    __shared__ float xs[D];
    __shared__ float sk[D];
    __shared__ float sq[D];
    __shared__ float red[8];
    const int tid = threadIdx.x;
    const int wave = tid >> 6;
    const int lane = tid & 63;

    fvec4* xs4 = (fvec4*)xs;
    fvec4* ks4 = (fvec4*)sk;
    fvec4* qs4 = (fvec4*)sq;
    const fvec4* x4 = (const fvec4*)x;
    const fvec4* k4g = (const fvec4*)(ws + D);
    const fvec4* q4g = (const fvec4*)ws;
    const fvec4* np4 = (const fvec4*)n_prev;
#pragma unroll
    for (int i = 0; i < 4; ++i) {
        int j = tid + i * 256;
        xs4[j] = x4[j];
        ks4[j] = k4g[j];
        qs4[j] = q4g[j];
    }
    __syncthreads();

    // block-redundant kq = k.q, npq = n_prev.q (identical fp32 everywhere)
    float kq = 0.f, npq = 0.f;
#pragma unroll
    for (int i = 0; i < 4; ++i) {
        int j = tid + i * 256;
        fvec4 q = qs4[j], k = ks4[j], np = np4[j];
        kq  += k.x * q.x + k.y * q.y + k.z * q.z + k.w * q.w;
        npq += np.x * q.x + np.y * q.y + np.z * q.z + np.w * q.w;
    }
    kq = wave_reduce_sum(kq);
    npq = wave_reduce_sum(npq);
    if (lane == 0) { red[wave] = kq; red[4 + wave] = npq; }
    __syncthreads();
    kq  = (red[0] + red[1]) + (red[2] + red[3]);
    npq = (red[4] + red[5]) + (red[6] + red[7]);

    const float i_t = expf(ws[16384]);
    const float f_t = sigmoidf(ws[16385]);
    const float nqt = f_t * npq + i_t * kq;          // n_t . q
    const float inv = 1.0f / fmaxf(fabsf(nqt), 1.0f);

    const int row = blockIdx.x * 4 + wave;           // [0, 4096)

    // v,o matvecs for this wave's row (interleaved load streams)
    const fvec4* Wv4 = (const fvec4*)(wv + (size_t)row * D);
    const fvec4* Wo4 = (const fvec4*)(wo + (size_t)row * D);
    float av0 = 0.f, av1 = 0.f, ao0 = 0.f, ao1 = 0.f;
#pragma unroll
    for (int it = 0; it < 16; it += 2) {
        fvec4 v0 = Wv4[it * 64 + lane];
        fvec4 v1 = Wv4[(it + 1) * 64 + lane];
        fvec4 o0 = Wo4[it * 64 + lane];
        fvec4 o1 = Wo4[(it + 1) * 64 + lane];
        fvec4 xv0 = xs4[it * 64 + lane];
        fvec4 xv1 = xs4[(it + 1) * 64 + lane];
        av0 += v0.x * xv0.x + v0.y * xv0.y + v0.z * xv0.z + v0.w * xv0.w;
        av1 += v1.x * xv1.x + v1.y * xv1.y + v1.z * xv1.z + v1.w * xv1.w;
        ao0 += o0.x * xv0.x + o0.y * xv0.y + o0.z * xv0.z + o0.w * xv0.w;
        ao1 += o1.x * xv1.x + o1.y * xv1.y + o1.z * xv1.z + o1.w * xv1.w;
    }
    float v = wave_reduce_sum(av0 + av1);
    float o = wave_reduce_sum(ao0 + ao1);
    v = __shfl(v, 0) + bv[row];                      // broadcast to all lanes
    o = sigmoidf(__shfl(o, 0) + bo[row]);

    // cell stream for this row
    const float vr = v * i_t;
    const fvec4* cp4 = (const fvec4*)(c_prev + (size_t)row * D);
    fvec4* co4 = (fvec4*)(c_out + (size_t)row * D);
    float dot = 0.f;
#pragma unroll
    for (int it = 0; it < 16; ++it) {
        int j = it * 64 + lane;
        fvec4 cp = __builtin_nontemporal_load(&cp4[j]);
        fvec4 kk = ks4[j];
        fvec4 qq = qs4[j];
        fvec4 ct;
        ct.x = f_t * cp.x + vr * kk.x;
        ct.y = f_t * cp.y + vr * kk.y;
        ct.z = f_t * cp.z + vr * kk.z;
        ct.w = f_t * cp.w + vr * kk.w;
        __builtin_nontemporal_store(ct, &co4[j]);
        dot += cp.x * qq.x + cp.y * qq.y + cp.z * qq.z + cp.w * qq.w;
    }
    dot = wave_reduce_sum(dot);
    if (lane == 0) {
        out[row] = o * (f_t * dot + i_t * kq * v) * inv;   // h_t
    }

    // n_t rows of this block (full k vector staged in LDS)
    if (tid < 4) {
        const int idx = blockIdx.x * 4 + tid;
        out[(size_t)4096 + (size_t)D * D + idx] = f_t * n_prev[idx] + i_t * sk[idx];
    }
}

extern "C" void kernel_launch(void* const* d_in, const int* in_sizes, int n_in,
                              void* d_out, int out_size, void* d_ws, size_t ws_size,
                              hipStream_t stream)
{
    const float* x      = (const float*)d_in[0];
    const float* c_prev = (const float*)d_in[1];
    const float* n_prev = (const float*)d_in[2];
    const float* wq = (const float*)d_in[3];  const float* bq  = (const float*)d_in[4];
    const float* wk = (const float*)d_in[5];  const float* bk  = (const float*)d_in[6];
    const float* wv = (const float*)d_in[7];  const float* bv  = (const float*)d_in[8];
    const float* wi = (const float*)d_in[9];  const float* bi  = (const float*)d_in[10];
    const float* wf = (const float*)d_in[11]; const float* bfv = (const float*)d_in[12];
    const float* wo = (const float*)d_in[13]; const float* bo  = (const float*)d_in[14];
    float* out = (float*)d_out;
    float* ws  = (float*)d_ws;

    qk_kernel<<<dim3(1025), dim3(256), 0, stream>>>(
        x, wq, bq, wk, bk, wi, bi, wf, bfv, ws);
    vocell_kernel<<<dim3(1024), dim3(256), 0, stream>>>(
        x, c_prev, n_prev, wv, bv, wo, bo, ws, out + D, out);
}